// Round 2
// baseline (2338.562 us; speedup 1.0000x reference)
//
#include <hip/hip_runtime.h>
#include <stdint.h>
#include <stddef.h>

typedef _Float16 half8 __attribute__((ext_vector_type(8)));
typedef _Float16 half4v __attribute__((ext_vector_type(4)));
typedef float f32x4 __attribute__((ext_vector_type(4)));

__device__ __forceinline__ void gload_lds16(const void* g, void* l) {
  __builtin_amdgcn_global_load_lds((const __attribute__((address_space(1))) void*)g,
                                   (__attribute__((address_space(3))) void*)l, 16, 0, 0);
}

// ---------------- transpose+cast: in (B,C,N) f32 -> out (B,N,C) f16 ----------------
__global__ __launch_bounds__(256) void k_transpose_cast(const float* __restrict__ in,
                                                        _Float16* __restrict__ out,
                                                        int C, int N) {
  __shared__ float tile[32][33];
  int b = blockIdx.z;
  int c0 = blockIdx.x * 32, n0 = blockIdx.y * 32;
  int tx = threadIdx.x, ty = threadIdx.y;
#pragma unroll
  for (int j = 0; j < 32; j += 8) {
    int c = c0 + ty + j, n = n0 + tx;
    if (c < C && n < N) tile[ty + j][tx] = in[((size_t)b * C + c) * N + n];
  }
  __syncthreads();
#pragma unroll
  for (int j = 0; j < 32; j += 8) {
    int n = n0 + ty + j, c = c0 + tx;
    if (n < N && c < C) out[((size_t)b * N + n) * C + c] = (_Float16)tile[tx][ty + j];
  }
}

// ---------------- weight cast with zero padding: (O,K) f32 -> (Opad,Kpad) f16 ----------------
__global__ __launch_bounds__(256) void k_cast_pad_w(const float* __restrict__ W,
                                                    _Float16* __restrict__ Wh,
                                                    int O, int K, int Opad, int Kpad) {
  size_t i = ((size_t)blockIdx.x * 256 + threadIdx.x) * 4;
  if (i >= (size_t)Opad * Kpad) return;
  int r = (int)(i / Kpad), k = (int)(i % Kpad);
  half4v v;
#pragma unroll
  for (int j = 0; j < 4; ++j) {
    float f = (r < O && (k + j) < K) ? W[(size_t)r * K + k + j] : 0.f;
    v[j] = (_Float16)f;
  }
  *(half4v*)(Wh + i) = v;
}

// ---------------- 3-NN + inverse-distance weights ----------------
__global__ __launch_bounds__(256) void k_knn3(const float* __restrict__ q, const float* __restrict__ p,
                                              int N1, int S, int4* __restrict__ idxo,
                                              float4* __restrict__ wo) {
  __shared__ float sp[512 * 3];
  __shared__ float spp[512];
  int b = blockIdx.y;
  for (int i = threadIdx.x; i < S * 3; i += 256) sp[i] = p[(size_t)b * S * 3 + i];
  __syncthreads();
  for (int s = threadIdx.x; s < S; s += 256)
    spp[s] = sp[s * 3] * sp[s * 3] + sp[s * 3 + 1] * sp[s * 3 + 1] + sp[s * 3 + 2] * sp[s * 3 + 2];
  __syncthreads();
  int n = blockIdx.x * 256 + threadIdx.x;
  if (n >= N1) return;
  const float* qp = q + ((size_t)b * N1 + n) * 3;
  float qx = qp[0], qy = qp[1], qz = qp[2];
  float qq = qx * qx + qy * qy + qz * qz;
  float d0 = 1e30f, d1 = 1e30f, d2 = 1e30f;
  int i0 = 0, i1 = 0, i2 = 0;
  for (int s = 0; s < S; ++s) {
    float d = qq + spp[s] - 2.f * (qx * sp[s * 3] + qy * sp[s * 3 + 1] + qz * sp[s * 3 + 2]);
    if (d < d0)      { d2 = d1; i2 = i1; d1 = d0; i1 = i0; d0 = d; i0 = s; }
    else if (d < d1) { d2 = d1; i2 = i1; d1 = d; i1 = s; }
    else if (d < d2) { d2 = d; i2 = s; }
  }
  float w0 = 1.f / (d0 + 1e-8f), w1 = 1.f / (d1 + 1e-8f), w2 = 1.f / (d2 + 1e-8f);
  float wsum = w0 + w1 + w2;
  int gi = b * N1 + n;
  idxo[gi] = make_int4(i0, i1, i2, 0);
  wo[gi] = make_float4(w0 / wsum, w1 / wsum, w2 / wsum, 0.f);
}

// ---------------- fused GEMM: virtual A[m,k] = concat(skip[m], interp(H)[m]) ----------------
// C[m,o] = sum_k A[m,k] * W[o,k].  W rows stride ldb, out f16 stride ldc.
// 128x128 tile, BK=64, 256 threads.
__global__ __launch_bounds__(256) void k_gemm_fused(const _Float16* __restrict__ skipT,
                                                    const _Float16* __restrict__ H,
                                                    const int4* __restrict__ idxb,
                                                    const float4* __restrict__ wb,
                                                    const _Float16* __restrict__ W,
                                                    _Float16* __restrict__ Cout,
                                                    int K, int ldb, int ldc,
                                                    int C1, int S, int N1) {
  __shared__ __align__(16) _Float16 lA[128 * 64];
  __shared__ __align__(16) _Float16 lB[128 * 64];
  __shared__ int4 sidx[128];
  __shared__ _Float16 swh[128][4];
  int tid = threadIdx.x;
  int m0 = blockIdx.x * 128;
  int o0 = blockIdx.y * 128;
  int C2 = K - C1;
  if (tid < 128) {
    int gr = m0 + tid;
    int4 id = idxb[gr];
    float4 w = wb[gr];
    int b = gr / N1;
    sidx[tid] = make_int4((b * S + id.x) * C2, (b * S + id.y) * C2, (b * S + id.z) * C2, 0);
    swh[tid][0] = (_Float16)w.x; swh[tid][1] = (_Float16)w.y;
    swh[tid][2] = (_Float16)w.z; swh[tid][3] = (_Float16)0.f;
  }
  __syncthreads();

  int lane = tid & 63, wv = tid >> 6;
  int wm = (wv & 1) * 64, wo = (wv >> 1) * 64;
  int lr = lane & 15, lq = lane >> 4;
  int trow = tid >> 3;          // 0..31
  int tseg = (tid & 7) * 8;     // 0,8,..,56

  f32x4 acc[4][4];
#pragma unroll
  for (int mi = 0; mi < 4; ++mi)
#pragma unroll
    for (int oi = 0; oi < 4; ++oi)
      acc[mi][oi] = (f32x4){0.f, 0.f, 0.f, 0.f};

  const _Float16* gB = W + (size_t)(o0 + trow) * ldb + tseg;

  for (int k0 = 0; k0 < K; k0 += 64) {
#pragma unroll
    for (int i = 0; i < 4; ++i)
      gload_lds16(gB + (size_t)(32 * i) * ldb + k0, lB + ((size_t)i * 256 + tid) * 8);
    int kk = k0 + tseg;
#pragma unroll
    for (int i = 0; i < 4; ++i) {
      int row = trow + 32 * i;
      half8 v;
      if (kk < C1) {
        v = *(const half8*)&skipT[(size_t)(m0 + row) * C1 + kk];
      } else {
        int off = kk - C1;
        int4 hb = sidx[row];
        half8 a  = *(const half8*)&H[(size_t)hb.x + off];
        half8 b2 = *(const half8*)&H[(size_t)hb.y + off];
        half8 c2 = *(const half8*)&H[(size_t)hb.z + off];
        v = a * swh[row][0] + b2 * swh[row][1] + c2 * swh[row][2];
      }
      *(half8*)&lA[((size_t)i * 256 + tid) * 8] = v;
    }
    __syncthreads();
#pragma unroll
    for (int ks = 0; ks < 64; ks += 32) {
      half8 af[4], bf[4];
#pragma unroll
      for (int mi = 0; mi < 4; ++mi)
        af[mi] = *(const half8*)&lA[(wm + mi * 16 + lr) * 64 + ks + lq * 8];
#pragma unroll
      for (int oi = 0; oi < 4; ++oi)
        bf[oi] = *(const half8*)&lB[(wo + oi * 16 + lr) * 64 + ks + lq * 8];
#pragma unroll
      for (int mi = 0; mi < 4; ++mi)
#pragma unroll
        for (int oi = 0; oi < 4; ++oi)
          acc[mi][oi] = __builtin_amdgcn_mfma_f32_16x16x32_f16(af[mi], bf[oi], acc[mi][oi], 0, 0, 0);
    }
    __syncthreads();
  }

#pragma unroll
  for (int mi = 0; mi < 4; ++mi)
#pragma unroll
    for (int oi = 0; oi < 4; ++oi) {
      int col = o0 + wo + oi * 16 + lr;
      int rowb = m0 + wm + mi * 16 + lq * 4;
#pragma unroll
      for (int r = 0; r < 4; ++r)
        Cout[(size_t)(rowb + r) * ldc + col] = (_Float16)acc[mi][oi][r];
    }
}

// ---------------- plain GEMM f16 -> f32 out, optional accumulate ----------------
__global__ __launch_bounds__(256) void k_gemm_acc(const _Float16* __restrict__ A,
                                                  const _Float16* __restrict__ W,
                                                  float* __restrict__ D,
                                                  int K, int lda, int ldb, int ldc, int accum) {
  __shared__ __align__(16) _Float16 lA[128 * 64];
  __shared__ __align__(16) _Float16 lB[128 * 64];
  int tid = threadIdx.x;
  int m0 = blockIdx.x * 128;
  int o0 = blockIdx.y * 128;
  int lane = tid & 63, wv = tid >> 6;
  int wm = (wv & 1) * 64, wo = (wv >> 1) * 64;
  int lr = lane & 15, lq = lane >> 4;
  int trow = tid >> 3, tseg = (tid & 7) * 8;

  f32x4 acc[4][4];
#pragma unroll
  for (int mi = 0; mi < 4; ++mi)
#pragma unroll
    for (int oi = 0; oi < 4; ++oi)
      acc[mi][oi] = (f32x4){0.f, 0.f, 0.f, 0.f};

  const _Float16* gA = A + (size_t)(m0 + trow) * lda + tseg;
  const _Float16* gB = W + (size_t)(o0 + trow) * ldb + tseg;

  for (int k0 = 0; k0 < K; k0 += 64) {
#pragma unroll
    for (int i = 0; i < 4; ++i) {
      gload_lds16(gA + (size_t)(32 * i) * lda + k0, lA + ((size_t)i * 256 + tid) * 8);
      gload_lds16(gB + (size_t)(32 * i) * ldb + k0, lB + ((size_t)i * 256 + tid) * 8);
    }
    __syncthreads();
#pragma unroll
    for (int ks = 0; ks < 64; ks += 32) {
      half8 af[4], bf[4];
#pragma unroll
      for (int mi = 0; mi < 4; ++mi)
        af[mi] = *(const half8*)&lA[(wm + mi * 16 + lr) * 64 + ks + lq * 8];
#pragma unroll
      for (int oi = 0; oi < 4; ++oi)
        bf[oi] = *(const half8*)&lB[(wo + oi * 16 + lr) * 64 + ks + lq * 8];
#pragma unroll
      for (int mi = 0; mi < 4; ++mi)
#pragma unroll
        for (int oi = 0; oi < 4; ++oi)
          acc[mi][oi] = __builtin_amdgcn_mfma_f32_16x16x32_f16(af[mi], bf[oi], acc[mi][oi], 0, 0, 0);
    }
    __syncthreads();
  }

#pragma unroll
  for (int mi = 0; mi < 4; ++mi)
#pragma unroll
    for (int oi = 0; oi < 4; ++oi) {
      int col = o0 + wo + oi * 16 + lr;
      int rowb = m0 + wm + mi * 16 + lq * 4;
#pragma unroll
      for (int r = 0; r < 4; ++r) {
        size_t idx = (size_t)(rowb + r) * ldc + col;
        float v = acc[mi][oi][r];
        if (accum) v += D[idx];
        D[idx] = v;
      }
    }
}

// ---------------- BN stats f16 ----------------
__global__ __launch_bounds__(256) void k_bn_stats(const _Float16* __restrict__ G,
                                                  float* __restrict__ sum, float* __restrict__ sumsq,
                                                  int M, int ld, int O, int msplit) {
  int c = blockIdx.x * 256 + threadIdx.x;
  if (c >= O) return;
  int m0 = blockIdx.y * msplit;
  int m1 = m0 + msplit; if (m1 > M) m1 = M;
  float s = 0.f, q = 0.f;
  for (int m = m0; m < m1; ++m) {
    float v = (float)G[(size_t)m * ld + c];
    s += v; q += v * v;
  }
  atomicAdd(&sum[c], s);
  atomicAdd(&sumsq[c], q);
}

__global__ __launch_bounds__(256) void k_bn_stats_f32(const float* __restrict__ G,
                                                      float* __restrict__ sum, float* __restrict__ sumsq,
                                                      int M, int ld, int O, int msplit) {
  int c = blockIdx.x * 256 + threadIdx.x;
  if (c >= O) return;
  int m0 = blockIdx.y * msplit;
  int m1 = m0 + msplit; if (m1 > M) m1 = M;
  float s = 0.f, q = 0.f;
  for (int m = m0; m < m1; ++m) {
    float v = G[(size_t)m * ld + c];
    s += v; q += v * v;
  }
  atomicAdd(&sum[c], s);
  atomicAdd(&sumsq[c], q);
}

__global__ __launch_bounds__(256) void k_bn_finalize(const float* __restrict__ sum,
                                                     const float* __restrict__ sumsq,
                                                     const float* __restrict__ g, const float* __restrict__ b,
                                                     float* __restrict__ scale, float* __restrict__ shiftv,
                                                     int O, int Opad, float invM) {
  int c = blockIdx.x * 256 + threadIdx.x;
  if (c >= Opad) return;
  if (c < O) {
    float mean = sum[c] * invM;
    float var = sumsq[c] * invM - mean * mean;
    float sc = g[c] * rsqrtf(var + 1e-5f);
    scale[c] = sc;
    shiftv[c] = b[c] - mean * sc;
  } else {
    scale[c] = 0.f;
    shiftv[c] = 0.f;
  }
}

// ---------------- normalize + relu, f16 in-place ----------------
__global__ __launch_bounds__(256) void k_bn_norm(_Float16* __restrict__ G,
                                                 const float* __restrict__ scale,
                                                 const float* __restrict__ shiftv,
                                                 size_t total8, int ld) {
  size_t i = (size_t)blockIdx.x * 256 + threadIdx.x;
  if (i >= total8) return;
  half8 v = *(half8*)&G[i * 8];
  int c0 = (int)((i * 8) % (size_t)ld);
#pragma unroll
  for (int j = 0; j < 8; ++j) {
    float f = (float)v[j] * scale[c0 + j] + shiftv[c0 + j];
    v[j] = (_Float16)fmaxf(f, 0.f);
  }
  *(half8*)&G[i * 8] = v;
}

// ---------------- normalize + relu, f32 in-place (vec4) ----------------
__global__ __launch_bounds__(256) void k_bn_norm_f32(float* __restrict__ G,
                                                     const float* __restrict__ scale,
                                                     const float* __restrict__ shiftv,
                                                     size_t total4, int ld) {
  size_t i = (size_t)blockIdx.x * 256 + threadIdx.x;
  if (i >= total4) return;
  float4 v = *(float4*)&G[i * 4];
  int c0 = (int)((i * 4) % (size_t)ld);
  v.x = fmaxf(v.x * scale[c0 + 0] + shiftv[c0 + 0], 0.f);
  v.y = fmaxf(v.y * scale[c0 + 1] + shiftv[c0 + 1], 0.f);
  v.z = fmaxf(v.z * scale[c0 + 2] + shiftv[c0 + 2], 0.f);
  v.w = fmaxf(v.w * scale[c0 + 3] + shiftv[c0 + 3], 0.f);
  *(float4*)&G[i * 4] = v;
}

// ---------------- final 1x256 dot per point (f32 in) ----------------
__global__ __launch_bounds__(256) void k_final_dot_f32(const float* __restrict__ H,
                                                       const float* __restrict__ w,
                                                       float* __restrict__ out, int Mtot) {
  int lane = threadIdx.x & 63, wv = threadIdx.x >> 6;
  int r = blockIdx.x * 4 + wv;
  if (r >= Mtot) return;
  const float* h = H + (size_t)r * 256;
  float s = 0.f;
  for (int c = lane; c < 256; c += 64) s += h[c] * w[c];
#pragma unroll
  for (int o = 32; o > 0; o >>= 1) s += __shfl_down(s, o, 64);
  if (lane == 0) out[r] = s;
}

extern "C" void kernel_launch(void* const* d_in, const int* in_sizes, int n_in,
                              void* d_out, int out_size, void* d_ws, size_t ws_size,
                              hipStream_t stream) {
  (void)in_sizes; (void)n_in; (void)out_size;
  const int B = 16;
  const float* xyzs[5]; const float* xs[5];
  for (int i = 0; i < 5; ++i) { xyzs[i] = (const float*)d_in[2 * i]; xs[i] = (const float*)d_in[2 * i + 1]; }
  const float* wlin[4] = {(const float*)d_in[10], (const float*)d_in[13], (const float*)d_in[16], (const float*)d_in[19]};
  const float* glin[4] = {(const float*)d_in[11], (const float*)d_in[14], (const float*)d_in[17], (const float*)d_in[20]};
  const float* blin[4] = {(const float*)d_in[12], (const float*)d_in[15], (const float*)d_in[18], (const float*)d_in[21]};
  const float* wdec0 = (const float*)d_in[22];
  const float* gdec  = (const float*)d_in[23];
  const float* bdec  = (const float*)d_in[24];
  const float* wdec1 = (const float*)d_in[25];
  float* outp = (float*)d_out;

  const int ch[5] = {64, 128, 256, 512, 1024};
  const int np[5] = {2048, 512, 128, 32, 8};

  char* base = (char*)d_ws;
  size_t off = 0;
  auto alloc = [&](size_t bytes) -> char* {
    char* p = base + off;
    off += (bytes + 255) & ~(size_t)255;
    return p;
  };

  // reused per-layer weight buffer (max: stage3 2048x1984 f16 = 8.1MB)
  _Float16* Wbuf = (_Float16*)alloc((size_t)2048 * 1984 * 2);
  _Float16* Wdec = (_Float16*)alloc((size_t)256 * 2048 * 2);   // w_dec0 cast, K padded to 2048
  _Float16* tT[5];
  for (int i = 0; i < 5; ++i) tT[i] = (_Float16*)alloc((size_t)B * np[i] * ch[i] * 2);
  int4* idxb = (int4*)alloc(32768 * sizeof(int4));
  float4* wb = (float4*)alloc(32768 * sizeof(float4));
  float* sum = (float*)alloc(2048 * sizeof(float) * 2);
  float* sumsq = sum + 2048;
  float* scale = (float*)alloc(2048 * sizeof(float));
  float* shiftv = (float*)alloc(2048 * sizeof(float));
  _Float16* G0 = (_Float16*)alloc((size_t)512 * 1536 * 2);
  _Float16* G1 = (_Float16*)alloc((size_t)2048 * 1792 * 2);
  _Float16* G2 = (_Float16*)alloc((size_t)8192 * 1920 * 2);
  _Float16* Gchunk = (_Float16*)alloc((size_t)32768 * 512 * 2);
  float* D = (float*)alloc((size_t)32768 * 256 * 4);
  if (off > ws_size) return;  // ~126 MB needed

  // features -> (B,N,C) f16
  for (int i = 0; i < 5; ++i) {
    dim3 g(ch[i] / 32, (np[i] + 31) / 32, B);
    k_transpose_cast<<<g, dim3(32, 8), 0, stream>>>(xs[i], tT[i], ch[i], np[i]);
  }
  // decoder conv0 weight: (256,1984) -> (256,2048) f16
  {
    size_t tot4 = (size_t)256 * 2048 / 4;
    k_cast_pad_w<<<dim3((unsigned)((tot4 + 255) / 256)), 256, 0, stream>>>(wdec0, Wdec, 256, 1984, 256, 2048);
  }

  const int N1s[4] = {32, 128, 512, 2048};
  const int Ss[4]  = {8, 32, 128, 512};
  const int C1s[4] = {512, 256, 128, 64};
  const int Os[4]  = {1536, 1792, 1920, 1984};
  _Float16* Gs[3] = {G0, G1, G2};

  // ---- stages 0..2: full-O fused GEMM + BN ----
  for (int st = 0; st < 3; ++st) {
    int N1 = N1s[st], S = Ss[st], C1 = C1s[st];
    int M = B * N1, K = C1s[st] + (Os[st] - 0) - (Os[st] - (C1s[st] == 512 ? 1024 : (C1s[st] == 256 ? 1536 : 1792))) ;
    // K = C1 + C2 explicitly:
    int C2 = (st == 0) ? 1024 : Os[st - 1];
    K = C1 + C2;
    int O = Os[st];
    const _Float16* H = (st == 0) ? tT[4] : Gs[st - 1];
    const _Float16* skipT = tT[3 - st];
    _Float16* G = Gs[st];

    size_t wtot4 = (size_t)O * K / 4;
    k_cast_pad_w<<<dim3((unsigned)((wtot4 + 255) / 256)), 256, 0, stream>>>(wlin[st], Wbuf, O, K, O, K);
    k_knn3<<<dim3((N1 + 255) / 256, B), 256, 0, stream>>>(xyzs[3 - st], xyzs[4 - st], N1, S, idxb, wb);
    k_gemm_fused<<<dim3(M / 128, O / 128), 256, 0, stream>>>(skipT, H, idxb, wb, Wbuf, G, K, K, O, C1, S, N1);
    hipMemsetAsync(sum, 0, 2048 * 2 * sizeof(float), stream);
    int msplit = 256, gy = (M + msplit - 1) / msplit;
    k_bn_stats<<<dim3((O + 255) / 256, gy), 256, 0, stream>>>(G, sum, sumsq, M, O, O, msplit);
    k_bn_finalize<<<(O + 255) / 256, 256, 0, stream>>>(sum, sumsq, glin[st], blin[st], scale, shiftv, O, O, 1.f / M);
    size_t tot8 = (size_t)M * O / 8;
    k_bn_norm<<<(unsigned)((tot8 + 255) / 256), 256, 0, stream>>>(G, scale, shiftv, tot8, O);
  }

  // ---- stage 3: O-chunked (4 x 512) fused GEMM + BN + decoder accumulate ----
  {
    int N1 = 2048, S = 512, C1 = 64, C2 = 1920, K = 1984, O = 1984, M = 32768;
    size_t wtot4 = (size_t)2048 * K / 4;
    k_cast_pad_w<<<dim3((unsigned)((wtot4 + 255) / 256)), 256, 0, stream>>>(wlin[3], Wbuf, O, K, 2048, K);
    k_knn3<<<dim3((N1 + 255) / 256, B), 256, 0, stream>>>(xyzs[0], xyzs[1], N1, S, idxb, wb);

    for (int c0 = 0; c0 < 2048; c0 += 512) {
      int Ovalid = O - c0; if (Ovalid > 512) Ovalid = 512;
      k_gemm_fused<<<dim3(M / 128, 4), 256, 0, stream>>>(tT[0], G2, idxb, wb,
                                                         Wbuf + (size_t)c0 * K, Gchunk,
                                                         K, K, 512, C1, S, N1);
      hipMemsetAsync(sum, 0, 2048 * 2 * sizeof(float), stream);
      int msplit = 256, gy = M / msplit;
      k_bn_stats<<<dim3(2, gy), 256, 0, stream>>>(Gchunk, sum, sumsq, M, 512, Ovalid, msplit);
      k_bn_finalize<<<2, 256, 0, stream>>>(sum, sumsq, glin[3] + c0, blin[3] + c0, scale, shiftv, Ovalid, 512, 1.f / M);
      size_t tot8 = (size_t)M * 512 / 8;
      k_bn_norm<<<(unsigned)((tot8 + 255) / 256), 256, 0, stream>>>(Gchunk, scale, shiftv, tot8, 512);
      // D (+)= Gchunk_norm (M x 512) * Wdec[:, c0:c0+512]^T
      k_gemm_acc<<<dim3(M / 128, 2), 256, 0, stream>>>(Gchunk, Wdec + c0, D, 512, 512, 2048, 256, c0 != 0);
    }
  }

  // ---- decoder BN + final dot ----
  {
    int M = 32768, O = 256;
    hipMemsetAsync(sum, 0, 2048 * 2 * sizeof(float), stream);
    int msplit = 256, gy = M / msplit;
    k_bn_stats_f32<<<dim3(1, gy), 256, 0, stream>>>(D, sum, sumsq, M, 256, O, msplit);
    k_bn_finalize<<<1, 256, 0, stream>>>(sum, sumsq, gdec, bdec, scale, shiftv, O, O, 1.f / M);
    size_t tot4 = (size_t)M * 256 / 4;
    k_bn_norm_f32<<<(unsigned)((tot4 + 255) / 256), 256, 0, stream>>>(D, scale, shiftv, tot4, 256);
    k_final_dot_f32<<<M / 4, 256, 0, stream>>>(D, wdec1, outp, M);
  }
}

// Round 3
// 1915.968 us; speedup vs baseline: 1.2206x; 1.2206x over previous
//
#include <hip/hip_runtime.h>
#include <stdint.h>
#include <stddef.h>

typedef _Float16 half8 __attribute__((ext_vector_type(8)));
typedef _Float16 half4v __attribute__((ext_vector_type(4)));
typedef float f32x4 __attribute__((ext_vector_type(4)));

__device__ __forceinline__ void gload_lds16(const void* g, void* l) {
  __builtin_amdgcn_global_load_lds((const __attribute__((address_space(1))) void*)g,
                                   (__attribute__((address_space(3))) void*)l, 16, 0, 0);
}

// ---------------- transpose+cast: in (B,C,N) f32 -> out (B,N,C) f16 ----------------
__global__ __launch_bounds__(256) void k_transpose_cast(const float* __restrict__ in,
                                                        _Float16* __restrict__ out,
                                                        int C, int N) {
  __shared__ float tile[32][33];
  int b = blockIdx.z;
  int c0 = blockIdx.x * 32, n0 = blockIdx.y * 32;
  int tx = threadIdx.x, ty = threadIdx.y;
#pragma unroll
  for (int j = 0; j < 32; j += 8) {
    int c = c0 + ty + j, n = n0 + tx;
    if (c < C && n < N) tile[ty + j][tx] = in[((size_t)b * C + c) * N + n];
  }
  __syncthreads();
#pragma unroll
  for (int j = 0; j < 32; j += 8) {
    int n = n0 + ty + j, c = c0 + tx;
    if (n < N && c < C) out[((size_t)b * N + n) * C + c] = (_Float16)tile[tx][ty + j];
  }
}

// ---------------- weight cast, K-pad only: (O,K) f32 -> (O,Kpad) f16 ----------------
__global__ __launch_bounds__(256) void k_cast_pad_w(const float* __restrict__ W,
                                                    _Float16* __restrict__ Wh,
                                                    int O, int K, int Opad, int Kpad) {
  size_t i = ((size_t)blockIdx.x * 256 + threadIdx.x) * 4;
  if (i >= (size_t)Opad * Kpad) return;
  int r = (int)(i / Kpad), k = (int)(i % Kpad);
  half4v v;
#pragma unroll
  for (int j = 0; j < 4; ++j) {
    float f = (r < O && (k + j) < K) ? W[(size_t)r * K + k + j] : 0.f;
    v[j] = (_Float16)f;
  }
  *(half4v*)(Wh + i) = v;
}

// ---------------- weight column-slice cast: Wh (Opad x Kw) = W[:, c0:c0+Kw], rows zero-padded ----
__global__ __launch_bounds__(256) void k_cast_slice_w(const float* __restrict__ W,
                                                      _Float16* __restrict__ Wh,
                                                      int O, int Ktot, int c0, int Kw, int Opad) {
  size_t i = ((size_t)blockIdx.x * 256 + threadIdx.x) * 4;
  if (i >= (size_t)Opad * Kw) return;
  int r = (int)(i / Kw), k = (int)(i % Kw);
  half4v v;
#pragma unroll
  for (int j = 0; j < 4; ++j) {
    float f = (r < O) ? W[(size_t)r * Ktot + c0 + k + j] : 0.f;
    v[j] = (_Float16)f;
  }
  *(half4v*)(Wh + i) = v;
}

// ---------------- 3-NN + inverse-distance weights ----------------
__global__ __launch_bounds__(256) void k_knn3(const float* __restrict__ q, const float* __restrict__ p,
                                              int N1, int S, int4* __restrict__ idxo,
                                              float4* __restrict__ wo) {
  __shared__ float sp[512 * 3];
  __shared__ float spp[512];
  int b = blockIdx.y;
  for (int i = threadIdx.x; i < S * 3; i += 256) sp[i] = p[(size_t)b * S * 3 + i];
  __syncthreads();
  for (int s = threadIdx.x; s < S; s += 256)
    spp[s] = sp[s * 3] * sp[s * 3] + sp[s * 3 + 1] * sp[s * 3 + 1] + sp[s * 3 + 2] * sp[s * 3 + 2];
  __syncthreads();
  int n = blockIdx.x * 256 + threadIdx.x;
  if (n >= N1) return;
  const float* qp = q + ((size_t)b * N1 + n) * 3;
  float qx = qp[0], qy = qp[1], qz = qp[2];
  float qq = qx * qx + qy * qy + qz * qz;
  float d0 = 1e30f, d1 = 1e30f, d2 = 1e30f;
  int i0 = 0, i1 = 0, i2 = 0;
  for (int s = 0; s < S; ++s) {
    float d = qq + spp[s] - 2.f * (qx * sp[s * 3] + qy * sp[s * 3 + 1] + qz * sp[s * 3 + 2]);
    if (d < d0)      { d2 = d1; i2 = i1; d1 = d0; i1 = i0; d0 = d; i0 = s; }
    else if (d < d1) { d2 = d1; i2 = i1; d1 = d; i1 = s; }
    else if (d < d2) { d2 = d; i2 = s; }
  }
  float w0 = 1.f / (d0 + 1e-8f), w1 = 1.f / (d1 + 1e-8f), w2 = 1.f / (d2 + 1e-8f);
  float wsum = w0 + w1 + w2;
  int gi = b * N1 + n;
  idxo[gi] = make_int4(i0, i1, i2, 0);
  wo[gi] = make_float4(w0 / wsum, w1 / wsum, w2 / wsum, 0.f);
}

// ---------------- GEMM with optional fused BN(norm)+ReLU on the A operand ----------------
// Cout[m,o] = sum_k f(A[m,k]) * W[o,k],  f(x) = apply_nr ? relu(x*scale[k]+shift[k]) : x
// 128x128 tile, BK=64, 256 threads. f16 output.
__global__ __launch_bounds__(256) void k_gemm_anorm(const _Float16* __restrict__ A,
                                                    const float* __restrict__ scale,
                                                    const float* __restrict__ shift,
                                                    int apply_nr,
                                                    const _Float16* __restrict__ W,
                                                    _Float16* __restrict__ Cout,
                                                    int K, int lda, int ldb, int ldc) {
  __shared__ __align__(16) _Float16 lA[128 * 64];
  __shared__ __align__(16) _Float16 lB[128 * 64];
  int tid = threadIdx.x;
  int m0 = blockIdx.x * 128;
  int o0 = blockIdx.y * 128;
  int lane = tid & 63, wv = tid >> 6;
  int wm = (wv & 1) * 64, wo = (wv >> 1) * 64;
  int lr = lane & 15, lq = lane >> 4;
  int trow = tid >> 3, tseg = (tid & 7) * 8;

  f32x4 acc[4][4];
#pragma unroll
  for (int mi = 0; mi < 4; ++mi)
#pragma unroll
    for (int oi = 0; oi < 4; ++oi)
      acc[mi][oi] = (f32x4){0.f, 0.f, 0.f, 0.f};

  const _Float16* gA = A + (size_t)(m0 + trow) * lda + tseg;
  const _Float16* gB = W + (size_t)(o0 + trow) * ldb + tseg;

  for (int k0 = 0; k0 < K; k0 += 64) {
#pragma unroll
    for (int i = 0; i < 4; ++i)
      gload_lds16(gB + (size_t)(32 * i) * ldb + k0, lB + ((size_t)i * 256 + tid) * 8);
    if (apply_nr) {
      float sc[8], sh[8];
#pragma unroll
      for (int j = 0; j < 8; ++j) { sc[j] = scale[k0 + tseg + j]; sh[j] = shift[k0 + tseg + j]; }
#pragma unroll
      for (int i = 0; i < 4; ++i) {
        half8 v = *(const half8*)(gA + (size_t)(32 * i) * lda + k0);
        half8 o;
#pragma unroll
        for (int j = 0; j < 8; ++j)
          o[j] = (_Float16)fmaxf((float)v[j] * sc[j] + sh[j], 0.f);
        *(half8*)&lA[((size_t)i * 256 + tid) * 8] = o;
      }
    } else {
#pragma unroll
      for (int i = 0; i < 4; ++i)
        gload_lds16(gA + (size_t)(32 * i) * lda + k0, lA + ((size_t)i * 256 + tid) * 8);
    }
    __syncthreads();
#pragma unroll
    for (int ks = 0; ks < 64; ks += 32) {
      half8 af[4], bf[4];
#pragma unroll
      for (int mi = 0; mi < 4; ++mi)
        af[mi] = *(const half8*)&lA[(wm + mi * 16 + lr) * 64 + ks + lq * 8];
#pragma unroll
      for (int oi = 0; oi < 4; ++oi)
        bf[oi] = *(const half8*)&lB[(wo + oi * 16 + lr) * 64 + ks + lq * 8];
#pragma unroll
      for (int mi = 0; mi < 4; ++mi)
#pragma unroll
        for (int oi = 0; oi < 4; ++oi)
          acc[mi][oi] = __builtin_amdgcn_mfma_f32_16x16x32_f16(af[mi], bf[oi], acc[mi][oi], 0, 0, 0);
    }
    __syncthreads();
  }

#pragma unroll
  for (int mi = 0; mi < 4; ++mi)
#pragma unroll
    for (int oi = 0; oi < 4; ++oi) {
      int col = o0 + wo + oi * 16 + lr;
      int rowb = m0 + wm + mi * 16 + lq * 4;
#pragma unroll
      for (int r = 0; r < 4; ++r)
        Cout[(size_t)(rowb + r) * ldc + col] = (_Float16)acc[mi][oi][r];
    }
}

// ---------------- GEMM, fused BN+ReLU on A, f32 accumulate into D ----------------
__global__ __launch_bounds__(256) void k_gemm_dec_acc(const _Float16* __restrict__ A,
                                                      const float* __restrict__ scale,
                                                      const float* __restrict__ shift,
                                                      const _Float16* __restrict__ W,
                                                      float* __restrict__ D,
                                                      int K, int lda, int ldb, int ldc, int accum) {
  __shared__ __align__(16) _Float16 lA[128 * 64];
  __shared__ __align__(16) _Float16 lB[128 * 64];
  int tid = threadIdx.x;
  int m0 = blockIdx.x * 128;
  int o0 = blockIdx.y * 128;
  int lane = tid & 63, wv = tid >> 6;
  int wm = (wv & 1) * 64, wo = (wv >> 1) * 64;
  int lr = lane & 15, lq = lane >> 4;
  int trow = tid >> 3, tseg = (tid & 7) * 8;

  f32x4 acc[4][4];
#pragma unroll
  for (int mi = 0; mi < 4; ++mi)
#pragma unroll
    for (int oi = 0; oi < 4; ++oi)
      acc[mi][oi] = (f32x4){0.f, 0.f, 0.f, 0.f};

  const _Float16* gA = A + (size_t)(m0 + trow) * lda + tseg;
  const _Float16* gB = W + (size_t)(o0 + trow) * ldb + tseg;

  for (int k0 = 0; k0 < K; k0 += 64) {
#pragma unroll
    for (int i = 0; i < 4; ++i)
      gload_lds16(gB + (size_t)(32 * i) * ldb + k0, lB + ((size_t)i * 256 + tid) * 8);
    float sc[8], sh[8];
#pragma unroll
    for (int j = 0; j < 8; ++j) { sc[j] = scale[k0 + tseg + j]; sh[j] = shift[k0 + tseg + j]; }
#pragma unroll
    for (int i = 0; i < 4; ++i) {
      half8 v = *(const half8*)(gA + (size_t)(32 * i) * lda + k0);
      half8 o;
#pragma unroll
      for (int j = 0; j < 8; ++j)
        o[j] = (_Float16)fmaxf((float)v[j] * sc[j] + sh[j], 0.f);
      *(half8*)&lA[((size_t)i * 256 + tid) * 8] = o;
    }
    __syncthreads();
#pragma unroll
    for (int ks = 0; ks < 64; ks += 32) {
      half8 af[4], bf[4];
#pragma unroll
      for (int mi = 0; mi < 4; ++mi)
        af[mi] = *(const half8*)&lA[(wm + mi * 16 + lr) * 64 + ks + lq * 8];
#pragma unroll
      for (int oi = 0; oi < 4; ++oi)
        bf[oi] = *(const half8*)&lB[(wo + oi * 16 + lr) * 64 + ks + lq * 8];
#pragma unroll
      for (int mi = 0; mi < 4; ++mi)
#pragma unroll
        for (int oi = 0; oi < 4; ++oi)
          acc[mi][oi] = __builtin_amdgcn_mfma_f32_16x16x32_f16(af[mi], bf[oi], acc[mi][oi], 0, 0, 0);
    }
    __syncthreads();
  }

#pragma unroll
  for (int mi = 0; mi < 4; ++mi)
#pragma unroll
    for (int oi = 0; oi < 4; ++oi) {
      int col = o0 + wo + oi * 16 + lr;
      int rowb = m0 + wm + mi * 16 + lq * 4;
#pragma unroll
      for (int r = 0; r < 4; ++r) {
        size_t idx = (size_t)(rowb + r) * ldc + col;
        float v = acc[mi][oi][r];
        if (accum) v += D[idx];
        D[idx] = v;
      }
    }
}

// ---------------- interp-add + BN stats: Y[r,:] += sum_j w_j * Z[idx_j,:], col sums/sumsq ----
// grid.x = M/128. Register partial sums per owned 8-col chunk, atomics at end.
__global__ __launch_bounds__(256) void k_interp_stats(_Float16* __restrict__ Y,
                                                      const _Float16* __restrict__ Z,
                                                      const int4* __restrict__ idxb,
                                                      const float4* __restrict__ wb,
                                                      float* __restrict__ sum,
                                                      float* __restrict__ sumsq,
                                                      int O, int ldy, int ldz, int zcol0,
                                                      int N1, int S) {
  __shared__ int4 sidx[128];
  __shared__ float4 swt[128];
  int r0 = blockIdx.x * 128;
  int tid = threadIdx.x;
  if (tid < 128) {
    int gr = r0 + tid;
    int4 id = idxb[gr];
    int b = gr / N1;
    sidx[tid] = make_int4((b * S + id.x) * ldz + zcol0, (b * S + id.y) * ldz + zcol0,
                          (b * S + id.z) * ldz + zcol0, 0);
    swt[tid] = wb[gr];
  }
  __syncthreads();
  int nch = O >> 3;              // 8-col chunks: 64..256
  int nrep = 256 / nch;          // 1 or 4
  int rep = tid / nch;
  int ch = tid - rep * nch;
  if (rep >= nrep) return;
  int rows = 128 / nrep;
  int rbeg = rep * rows;
  int c8 = ch * 8;
  float s[8], q[8];
#pragma unroll
  for (int j = 0; j < 8; ++j) { s[j] = 0.f; q[j] = 0.f; }
  for (int i = 0; i < rows; ++i) {
    int lrow = rbeg + i;
    int4 hb = sidx[lrow];
    float4 w = swt[lrow];
    size_t yoff = (size_t)(r0 + lrow) * ldy + c8;
    half8 y = *(half8*)&Y[yoff];
    half8 a  = *(const half8*)&Z[(size_t)hb.x + c8];
    half8 b2 = *(const half8*)&Z[(size_t)hb.y + c8];
    half8 c2 = *(const half8*)&Z[(size_t)hb.z + c8];
    half8 o;
#pragma unroll
    for (int j = 0; j < 8; ++j) {
      float v = (float)y[j] + w.x * (float)a[j] + w.y * (float)b2[j] + w.z * (float)c2[j];
      o[j] = (_Float16)v;
      s[j] += v; q[j] += v * v;
    }
    *(half8*)&Y[yoff] = o;
  }
#pragma unroll
  for (int j = 0; j < 8; ++j) {
    atomicAdd(&sum[c8 + j], s[j]);
    atomicAdd(&sumsq[c8 + j], q[j]);
  }
}

// ---------------- BN stats over f32 D ----------------
__global__ __launch_bounds__(256) void k_bn_stats_f32(const float* __restrict__ G,
                                                      float* __restrict__ sum, float* __restrict__ sumsq,
                                                      int M, int ld, int O, int msplit) {
  int c = blockIdx.x * 256 + threadIdx.x;
  if (c >= O) return;
  int m0 = blockIdx.y * msplit;
  int m1 = m0 + msplit; if (m1 > M) m1 = M;
  float s = 0.f, q = 0.f;
  for (int m = m0; m < m1; ++m) {
    float v = G[(size_t)m * ld + c];
    s += v; q += v * v;
  }
  atomicAdd(&sum[c], s);
  atomicAdd(&sumsq[c], q);
}

__global__ __launch_bounds__(256) void k_bn_finalize(const float* __restrict__ sum,
                                                     const float* __restrict__ sumsq,
                                                     const float* __restrict__ g, const float* __restrict__ b,
                                                     float* __restrict__ scale, float* __restrict__ shiftv,
                                                     int O, int Opad, float invM) {
  int c = blockIdx.x * 256 + threadIdx.x;
  if (c >= Opad) return;
  if (c < O) {
    float mean = sum[c] * invM;
    float var = sumsq[c] * invM - mean * mean;
    float sc = g[c] * rsqrtf(var + 1e-5f);
    scale[c] = sc;
    shiftv[c] = b[c] - mean * sc;
  } else {
    scale[c] = 0.f;
    shiftv[c] = 0.f;
  }
}

// ---------------- final dot with fused BN+ReLU: out[r] = sum_c relu(D*sc+sh)*w ----------------
__global__ __launch_bounds__(256) void k_final_dot_f32(const float* __restrict__ H,
                                                       const float* __restrict__ w,
                                                       const float* __restrict__ scale,
                                                       const float* __restrict__ shiftv,
                                                       float* __restrict__ out, int Mtot) {
  int lane = threadIdx.x & 63, wv = threadIdx.x >> 6;
  int r = blockIdx.x * 4 + wv;
  if (r >= Mtot) return;
  const float* h = H + (size_t)r * 256;
  float s = 0.f;
  for (int c = lane; c < 256; c += 64)
    s += fmaxf(h[c] * scale[c] + shiftv[c], 0.f) * w[c];
#pragma unroll
  for (int o = 32; o > 0; o >>= 1) s += __shfl_down(s, o, 64);
  if (lane == 0) out[r] = s;
}

extern "C" void kernel_launch(void* const* d_in, const int* in_sizes, int n_in,
                              void* d_out, int out_size, void* d_ws, size_t ws_size,
                              hipStream_t stream) {
  (void)in_sizes; (void)n_in; (void)out_size;
  const int B = 16;
  const float* xyzs[5]; const float* xs[5];
  for (int i = 0; i < 5; ++i) { xyzs[i] = (const float*)d_in[2 * i]; xs[i] = (const float*)d_in[2 * i + 1]; }
  const float* wlin[4] = {(const float*)d_in[10], (const float*)d_in[13], (const float*)d_in[16], (const float*)d_in[19]};
  const float* glin[4] = {(const float*)d_in[11], (const float*)d_in[14], (const float*)d_in[17], (const float*)d_in[20]};
  const float* blin[4] = {(const float*)d_in[12], (const float*)d_in[15], (const float*)d_in[18], (const float*)d_in[21]};
  const float* wdec0 = (const float*)d_in[22];
  const float* gdec  = (const float*)d_in[23];
  const float* bdec  = (const float*)d_in[24];
  const float* wdec1 = (const float*)d_in[25];
  float* outp = (float*)d_out;

  const int ch[5] = {64, 128, 256, 512, 1024};
  const int np[5] = {2048, 512, 128, 32, 8};

  char* base = (char*)d_ws;
  size_t off = 0;
  auto alloc = [&](size_t bytes) -> char* {
    char* p = base + off;
    off += (bytes + 255) & ~(size_t)255;
    return p;
  };

  _Float16* Wint  = (_Float16*)alloc((size_t)2048 * 1920 * 2);  // interp-part weights (padded rows)
  _Float16* Wskip = (_Float16*)alloc((size_t)1536 * 512 * 2);   // skip-part weights
  _Float16* Wdec  = (_Float16*)alloc((size_t)256 * 2048 * 2);   // w_dec0, K padded to 2048
  _Float16* tT[5];
  for (int i = 0; i < 5; ++i) tT[i] = (_Float16*)alloc((size_t)B * np[i] * ch[i] * 2);
  int4* idxb = (int4*)alloc(32768 * sizeof(int4));
  float4* wb = (float4*)alloc(32768 * sizeof(float4));
  float* sum    = (float*)alloc(2048 * sizeof(float));
  float* sumsq  = (float*)alloc(2048 * sizeof(float));
  float* scaleA = (float*)alloc(2048 * sizeof(float));
  float* shiftA = (float*)alloc(2048 * sizeof(float));
  float* scaleC = (float*)alloc(2048 * sizeof(float));
  float* shiftC = (float*)alloc(2048 * sizeof(float));
  _Float16* Zreg = (_Float16*)alloc((size_t)8192 * 2048 * 2);   // stage Z (ld=O) / full Z3 (ld=2048)
  char* Yreg = alloc((size_t)40370176);                          // Y0|Y1|Y2 ; Ychunk aliases base
  _Float16* Y0 = (_Float16*)Yreg;
  _Float16* Y1 = (_Float16*)(Yreg + (size_t)512 * 1536 * 2);
  _Float16* Y2 = (_Float16*)(Yreg + (size_t)(512 * 1536 + 2048 * 1792) * 2);
  _Float16* Ychunk = (_Float16*)Yreg;                            // 32768x512 f16, stage-3 only
  float* D = (float*)alloc((size_t)32768 * 256 * 4);
  if (off > ws_size) return;  // ~128 MB needed

  // features -> (B,N,C) f16
  for (int i = 0; i < 5; ++i) {
    dim3 g(ch[i] / 32, (np[i] + 31) / 32, B);
    k_transpose_cast<<<g, dim3(32, 8), 0, stream>>>(xs[i], tT[i], ch[i], np[i]);
  }
  // decoder conv0 weight
  {
    size_t tot4 = (size_t)256 * 2048 / 4;
    k_cast_pad_w<<<dim3((unsigned)((tot4 + 255) / 256)), 256, 0, stream>>>(wdec0, Wdec, 256, 1984, 256, 2048);
  }

  const int N1s[4] = {32, 128, 512, 2048};
  const int Ss[4]  = {8, 32, 128, 512};
  const int C1s[4] = {512, 256, 128, 64};
  const int C2s[4] = {1024, 1536, 1792, 1920};
  const int Os[4]  = {1536, 1792, 1920, 1984};
  _Float16* Ys[3] = {Y0, Y1, Y2};

  // ---- stages 0..2 ----
  for (int st = 0; st < 3; ++st) {
    int N1 = N1s[st], S = Ss[st], C1 = C1s[st], C2 = C2s[st], O = Os[st];
    int M = B * N1, Msrc = B * S;
    const _Float16* H = (st == 0) ? tT[4] : Ys[st - 1];
    _Float16* Y = Ys[st];

    size_t ti = (size_t)O * C2 / 4;
    k_cast_slice_w<<<(unsigned)((ti + 255) / 256), 256, 0, stream>>>(wlin[st], Wint, O, C1 + C2, C1, C2, O);
    size_t ts = (size_t)O * C1 / 4;
    k_cast_slice_w<<<(unsigned)((ts + 255) / 256), 256, 0, stream>>>(wlin[st], Wskip, O, C1 + C2, 0, C1, O);
    k_knn3<<<dim3((N1 + 255) / 256, B), 256, 0, stream>>>(xyzs[3 - st], xyzs[4 - st], N1, S, idxb, wb);

    // Z = normrelu(H) . Wint^T   (raw H for st==0)
    k_gemm_anorm<<<dim3(Msrc / 128, O / 128), 256, 0, stream>>>(H, scaleA, shiftA, st != 0,
                                                                Wint, Zreg, C2, C2, C2, O);
    // Y = skip . Wskip^T  (raw skip)
    k_gemm_anorm<<<dim3(M / 128, O / 128), 256, 0, stream>>>(tT[3 - st], scaleA, shiftA, 0,
                                                             Wskip, Y, C1, C1, C1, O);
    hipMemsetAsync(sum, 0, 2048 * sizeof(float), stream);
    hipMemsetAsync(sumsq, 0, 2048 * sizeof(float), stream);
    k_interp_stats<<<M / 128, 256, 0, stream>>>(Y, Zreg, idxb, wb, sum, sumsq, O, O, O, 0, N1, S);
    k_bn_finalize<<<(O + 255) / 256, 256, 0, stream>>>(sum, sumsq, glin[st], blin[st], scaleA, shiftA, O, O, 1.f / M);
  }

  // ---- stage 3: full Z3 once, then O-chunked Y + dec0 accumulation ----
  {
    int N1 = 2048, S = 512, C1 = 64, C2 = 1920, O = 1984, M = 32768, Msrc = 8192;
    size_t ti = (size_t)2048 * C2 / 4;
    k_cast_slice_w<<<(unsigned)((ti + 255) / 256), 256, 0, stream>>>(wlin[3], Wint, O, C1 + C2, C1, C2, 2048);
    size_t ts = (size_t)2048 * C1 / 4;
    k_cast_slice_w<<<(unsigned)((ts + 255) / 256), 256, 0, stream>>>(wlin[3], Wskip, O, C1 + C2, 0, C1, 2048);
    k_knn3<<<dim3((N1 + 255) / 256, B), 256, 0, stream>>>(xyzs[0], xyzs[1], N1, S, idxb, wb);

    // Z3 (8192 x 2048) = normrelu(Y2) . Wint^T   -- uses stage-2 scale/shift
    k_gemm_anorm<<<dim3(Msrc / 128, 16), 256, 0, stream>>>(Y2, scaleA, shiftA, 1,
                                                           Wint, Zreg, C2, C2, C2, 2048);

    for (int c0 = 0; c0 < 2048; c0 += 512) {
      int Ovalid = O - c0; if (Ovalid > 512) Ovalid = 512;
      // Ychunk = skip . Wskip[c0:c0+512]^T
      k_gemm_anorm<<<dim3(M / 128, 4), 256, 0, stream>>>(tT[0], scaleA, shiftA, 0,
                                                         Wskip + (size_t)c0 * C1, Ychunk, C1, C1, C1, 512);
      hipMemsetAsync(sum, 0, 2048 * sizeof(float), stream);
      hipMemsetAsync(sumsq, 0, 2048 * sizeof(float), stream);
      k_interp_stats<<<M / 128, 256, 0, stream>>>(Ychunk, Zreg, idxb, wb, sum, sumsq,
                                                  512, 512, 2048, c0, N1, S);
      k_bn_finalize<<<2, 256, 0, stream>>>(sum, sumsq, glin[3] + c0, blin[3] + c0, scaleC, shiftC,
                                           Ovalid, 512, 1.f / M);
      // D (+)= normrelu(Ychunk) . Wdec[:, c0:c0+512]^T
      k_gemm_dec_acc<<<dim3(M / 128, 2), 256, 0, stream>>>(Ychunk, scaleC, shiftC,
                                                           Wdec + c0, D, 512, 512, 2048, 256, c0 != 0);
    }
  }

  // ---- decoder BN + final dot ----
  {
    int M = 32768, O = 256;
    hipMemsetAsync(sum, 0, 2048 * sizeof(float), stream);
    hipMemsetAsync(sumsq, 0, 2048 * sizeof(float), stream);
    k_bn_stats_f32<<<dim3(1, M / 256), 256, 0, stream>>>(D, sum, sumsq, M, 256, O, 256);
    k_bn_finalize<<<1, 256, 0, stream>>>(sum, sumsq, gdec, bdec, scaleC, shiftC, O, O, 1.f / M);
    k_final_dot_f32<<<M / 4, 256, 0, stream>>>(D, wdec1, scaleC, shiftC, outp, M);
  }
}